// Round 2
// baseline (89.641 us; speedup 1.0000x reference)
//
#include <hip/hip_runtime.h>
#include <math.h>

// Problem constants (from reference)
#define B_N    32768
#define P_N    128
#define X_N    30
#define Y_N    30
#define F_N    6
#define CELLS  (X_N * Y_N)      // 900
#define ROW_F  (CELLS * F_N)    // 5400 floats per p
#define INV_T  1000.0f          // 1 / 0.001
#define POISON 0xAAAAAAAAu      // harness re-poisons d_ws to 0xAA bytes

// Single ordinary dispatch, 256 blocks x 256 threads.
//
// Phase 1 (blocks 0..224): wave w handles cell = blockIdx*4 + w (225*4 = 900).
//   V[cell] = sum_p softmax_p(s/T)*s, s = dot(sf[p,cell,:], w).
//   Stored with agent-scope relaxed atomic stores (visible cross-XCD), then
//   each producer block does ONE release fetch_add(+4) on a done-counter.
//
// Phase 2 (all 256 blocks): gate on the single counter word instead of
//   spinning on all 900 V words. Rationale (rocprof round 0): the per-element
//   spin issued ~230K agent-scope loads per round over 57 cache lines at the
//   coherence point, serializing MALL banks and contending with the
//   producers' own stores (priority inversion) -> ~25us kernel part. The
//   counter gate is one line; same-address wave loads coalesce to one
//   transaction; post-gate V staging is one round trip of 4 independent
//   loads per thread instead of 4 serial spins.
//
// Hardening vs round 1 (container failed, no profile): the gate spin is
//   BOUNDED. If it ever fails to open (any unforeseen counter issue), we
//   fall through to the per-element poison spin below, which is exactly the
//   previously harness-verified sync of the 64.7us baseline. Hang risk is
//   therefore no worse than the proven kernel; fast path unchanged.
__global__ __launch_bounds__(256) void fused_kernel(
    const float* __restrict__ phi, const float* __restrict__ sf,
    const float* __restrict__ w, float* __restrict__ V,
    float* __restrict__ out)
{
    const int tid  = threadIdx.x;
    const int lane = tid & 63;
    const int wave = tid >> 6;

    const float w0 = w[0], w1 = w[1], w2 = w[2],
                w3 = w[3], w4 = w[4], w5 = w[5];

    unsigned int* Vu  = (unsigned int*)V;
    unsigned int* cnt = Vu + CELLS;   // d_ws word 900, also poison-initialized

    // ---------------- Phase 1: build V table (blocks 0..224) ----------------
    if (blockIdx.x < 225) {
        const int cell = blockIdx.x * 4 + wave;   // 0..899

        const float* r0 = sf + (size_t)lane * ROW_F + cell * F_N;
        const float* r1 = r0 + (size_t)64 * ROW_F;

        float2 a0 = *(const float2*)(r0);
        float2 a1 = *(const float2*)(r0 + 2);
        float2 a2 = *(const float2*)(r0 + 4);
        float2 b0 = *(const float2*)(r1);
        float2 b1 = *(const float2*)(r1 + 2);
        float2 b2 = *(const float2*)(r1 + 4);

        float d0 = a0.x*w0 + a0.y*w1 + a1.x*w2 + a1.y*w3 + a2.x*w4 + a2.y*w5;
        float d1 = b0.x*w0 + b0.y*w1 + b1.x*w2 + b1.y*w3 + b2.x*w4 + b2.y*w5;

        float m = fmaxf(d0, d1);
#pragma unroll
        for (int off = 32; off >= 1; off >>= 1)
            m = fmaxf(m, __shfl_xor(m, off, 64));

        float e0 = __expf((d0 - m) * INV_T);
        float e1 = __expf((d1 - m) * INV_T);
        float num = e0 * d0 + e1 * d1;
        float den = e0 + e1;
#pragma unroll
        for (int off = 32; off >= 1; off >>= 1) {
            num += __shfl_xor(num, off, 64);
            den += __shfl_xor(den, off, 64);
        }

        if (lane == 0) {
            float val = num / den;
            __hip_atomic_store(&Vu[cell], __float_as_uint(val),
                               __ATOMIC_RELAXED, __HIP_MEMORY_SCOPE_AGENT);
        }

        // One release-add per block (225 RMWs total vs 900 flag stores):
        // __syncthreads() drains every wave's V store (s_waitcnt vmcnt(0)
        // before s_barrier) so the release-add publishes all 4 cells.
        __syncthreads();
        if (tid == 0)
            __hip_atomic_fetch_add(cnt, 4u, __ATOMIC_RELEASE,
                                   __HIP_MEMORY_SCOPE_AGENT);
    }

    // ---------------- Phase 2: per-output epilogue (all blocks) -------------
    const int o = blockIdx.x * 256 + tid;   // 0..65535 == B_N*2 outputs
    const int b = o >> 1;
    const int side = o & 1;

    // Prefetch phi BEFORE the gate so HBM latency overlaps the wait.
    // phi layout: [B, 2, 10] -> 20 floats per b, 16B-aligned (80B stride).
    const float4* p4 = (const float4*)(phi + (size_t)b * 20);
    float4 c0 = p4[0];  // t0: f0 f1 f2 f3
    float4 c1 = p4[1];  // t0: f4 f5 x_ss y_ss
    float4 c2 = p4[2];  // t0: x_es y_es | t1: f0 f1
    float4 c3 = p4[3];  // t1: f2 f3 f4 f5
    float4 c4 = p4[4];  // t1: x_ss y_ss x_es y_es

    // Gate: bounded spin on ONE counter line (relaxed + s_sleep throttle),
    // then one acquire fence orders the V loads below. On timeout we simply
    // fall through — the per-element poison spin is the correctness backstop.
    {
        unsigned int c = __hip_atomic_load(cnt, __ATOMIC_RELAXED,
                                           __HIP_MEMORY_SCOPE_AGENT);
        int guard = 1 << 22;
        while ((unsigned int)(c - POISON) < (unsigned int)CELLS && --guard) {
            __builtin_amdgcn_s_sleep(2);
            c = __hip_atomic_load(cnt, __ATOMIC_RELAXED,
                                  __HIP_MEMORY_SCOPE_AGENT);
        }
        __builtin_amdgcn_fence(__ATOMIC_ACQUIRE, "agent");
    }

    // Stage V into LDS: 4 independent one-shot loads per thread (single
    // round trip on the fast path). Poison re-check is the proven backstop;
    // it never loops once the counter has opened.
    __shared__ float Vs[CELLS];
    for (int i = tid; i < CELLS; i += 256) {
        unsigned int u = __hip_atomic_load(&Vu[i], __ATOMIC_RELAXED,
                                           __HIP_MEMORY_SCOPE_AGENT);
        while (u == POISON) {
            __builtin_amdgcn_s_sleep(1);
            u = __hip_atomic_load(&Vu[i], __ATOMIC_RELAXED,
                                  __HIP_MEMORY_SCOPE_AGENT);
        }
        Vs[i] = __uint_as_float(u);
    }
    __syncthreads();

    float pr0 = c0.x*w0 + c0.y*w1 + c0.z*w2 + c0.w*w3 + c1.x*w4 + c1.y*w5;
    float pr1 = c2.z*w0 + c2.w*w1 + c3.x*w2 + c3.y*w3 + c3.z*w4 + c3.w*w5;

    int iss0 = (int)c1.z * Y_N + (int)c1.w;
    int ies0 = (int)c2.x * Y_N + (int)c2.y;
    int iss1 = (int)c4.x * Y_N + (int)c4.y;
    int ies1 = (int)c4.z * Y_N + (int)c4.w;

    float d0 = pr0 + Vs[ies0] - Vs[iss0];
    float d1 = pr1 + Vs[ies1] - Vs[iss1];

    float x = side ? (d1 - d0) : (d0 - d1);
    out[o] = 1.0f / (1.0f + expf(-x));
}

// ---------------------------------------------------------------------------
extern "C" void kernel_launch(void* const* d_in, const int* in_sizes, int n_in,
                              void* d_out, int out_size, void* d_ws, size_t ws_size,
                              hipStream_t stream) {
    const float* phi = (const float*)d_in[0];   // (B, 2, 10)
    const float* sf  = (const float*)d_in[1];   // (P, X, Y, F)
    const float* w   = (const float*)d_in[2];   // (F,)
    float* out = (float*)d_out;                 // (B, 2, 1)
    float* V   = (float*)d_ws;                  // 901 floats scratch (poisoned 0xAA)

    fused_kernel<<<256, 256, 0, stream>>>(phi, sf, w, V, out);
}

// Round 3
// 62.193 us; speedup vs baseline: 1.4413x; 1.4413x over previous
//
#include <hip/hip_runtime.h>
#include <math.h>

// Problem constants (from reference)
#define B_N    32768
#define P_N    128
#define X_N    30
#define Y_N    30
#define F_N    6
#define CELLS  (X_N * Y_N)      // 900
#define ROW_F  (CELLS * F_N)    // 5400 floats per p
#define INV_T  1000.0f          // 1 / 0.001

// Two stream-ordered dispatches replace the single-dispatch spin protocol.
//
// Post-mortem of the spin designs (rocprof rounds 0-2):
//  - per-element poison spin (baseline): kernel part ~25us — 230K agent-scope
//    spin loads/round over 57 MALL lines, contending with producer stores.
//  - counter gate + release/acquire (round 2): kernel part ~47us — WORSE.
//    Agent-scope RELEASE RMW emits buffer_wbl2 (L2 writeback) x225 and the
//    ACQUIRE fence emits buffer_inv x256, each a 4-MiB L2 tag walk on an L2
//    left dirty by the 256-MiB poison fill. Fence cost >> spin cost.
//
// Stream ordering gives the V->epilogue dependency for free: the dispatch
// boundary performs visibility maintenance ONCE (command processor), with no
// waves spinning and no per-block cache-maintenance ops. d_ws poison is now
// irrelevant (kernel 1 overwrites all 900 V words before kernel 2 reads).

// ---------------- Kernel 1: build V table ----------------
// 225 blocks x 256 threads; wave w handles cell = blockIdx*4 + w (225*4=900).
// V[cell] = sum_p softmax_p(s/T)*s,  s = dot(sf[p,cell,:], w).
__global__ __launch_bounds__(256) void v_kernel(
    const float* __restrict__ sf, const float* __restrict__ w,
    float* __restrict__ V)
{
    const int tid  = threadIdx.x;
    const int lane = tid & 63;
    const int wave = tid >> 6;
    const int cell = blockIdx.x * 4 + wave;   // 0..899

    const float w0 = w[0], w1 = w[1], w2 = w[2],
                w3 = w[3], w4 = w[4], w5 = w[5];

    // lane p and p+64; rows are 24B, 8B-aligned -> float2 loads.
    const float* r0 = sf + (size_t)lane * ROW_F + cell * F_N;
    const float* r1 = r0 + (size_t)64 * ROW_F;

    float2 a0 = *(const float2*)(r0);
    float2 a1 = *(const float2*)(r0 + 2);
    float2 a2 = *(const float2*)(r0 + 4);
    float2 b0 = *(const float2*)(r1);
    float2 b1 = *(const float2*)(r1 + 2);
    float2 b2 = *(const float2*)(r1 + 4);

    float d0 = a0.x*w0 + a0.y*w1 + a1.x*w2 + a1.y*w3 + a2.x*w4 + a2.y*w5;
    float d1 = b0.x*w0 + b0.y*w1 + b1.x*w2 + b1.y*w3 + b2.x*w4 + b2.y*w5;

    float m = fmaxf(d0, d1);
#pragma unroll
    for (int off = 32; off >= 1; off >>= 1)
        m = fmaxf(m, __shfl_xor(m, off, 64));

    float e0 = __expf((d0 - m) * INV_T);
    float e1 = __expf((d1 - m) * INV_T);
    float num = e0 * d0 + e1 * d1;
    float den = e0 + e1;
#pragma unroll
    for (int off = 32; off >= 1; off >>= 1) {
        num += __shfl_xor(num, off, 64);
        den += __shfl_xor(den, off, 64);
    }

    if (lane == 0)
        V[cell] = num / den;   // plain store; dispatch boundary publishes it
}

// ---------------- Kernel 2: per-output epilogue ----------------
// 128 blocks x 512 threads, one thread per output element (65536 total).
__global__ __launch_bounds__(512) void out_kernel(
    const float* __restrict__ phi, const float* __restrict__ w,
    const float* __restrict__ V, float* __restrict__ out)
{
    const int tid = threadIdx.x;
    const int o = blockIdx.x * 512 + tid;   // 0..65535 == B_N*2 outputs
    const int b = o >> 1;
    const int side = o & 1;

    // phi layout: [B, 2, 10] -> 20 floats per b, 16B-aligned (80B stride).
    // Issue these independent loads first so they overlap the V staging.
    const float4* p4 = (const float4*)(phi + (size_t)b * 20);
    float4 c0 = p4[0];  // t0: f0 f1 f2 f3
    float4 c1 = p4[1];  // t0: f4 f5 x_ss y_ss
    float4 c2 = p4[2];  // t0: x_es y_es | t1: f0 f1
    float4 c3 = p4[3];  // t1: f2 f3 f4 f5
    float4 c4 = p4[4];  // t1: x_ss y_ss x_es y_es

    const float w0 = w[0], w1 = w[1], w2 = w[2],
                w3 = w[3], w4 = w[4], w5 = w[5];

    // Stage V into LDS (2 strided rounds of plain loads; V is L2/MALL-hot
    // from kernel 1).
    __shared__ float Vs[CELLS];
#pragma unroll
    for (int i = tid; i < CELLS; i += 512)
        Vs[i] = V[i];
    __syncthreads();

    float pr0 = c0.x*w0 + c0.y*w1 + c0.z*w2 + c0.w*w3 + c1.x*w4 + c1.y*w5;
    float pr1 = c2.z*w0 + c2.w*w1 + c3.x*w2 + c3.y*w3 + c3.z*w4 + c3.w*w5;

    int iss0 = (int)c1.z * Y_N + (int)c1.w;
    int ies0 = (int)c2.x * Y_N + (int)c2.y;
    int iss1 = (int)c4.x * Y_N + (int)c4.y;
    int ies1 = (int)c4.z * Y_N + (int)c4.w;

    float d0 = pr0 + Vs[ies0] - Vs[iss0];
    float d1 = pr1 + Vs[ies1] - Vs[iss1];

    float x = side ? (d1 - d0) : (d0 - d1);
    out[o] = 1.0f / (1.0f + expf(-x));
}

// ---------------------------------------------------------------------------
extern "C" void kernel_launch(void* const* d_in, const int* in_sizes, int n_in,
                              void* d_out, int out_size, void* d_ws, size_t ws_size,
                              hipStream_t stream) {
    const float* phi = (const float*)d_in[0];   // (B, 2, 10)
    const float* sf  = (const float*)d_in[1];   // (P, X, Y, F)
    const float* w   = (const float*)d_in[2];   // (F,)
    float* out = (float*)d_out;                 // (B, 2, 1)
    float* V   = (float*)d_ws;                  // 900 floats scratch

    v_kernel<<<225, 256, 0, stream>>>(sf, w, V);
    out_kernel<<<128, 512, 0, stream>>>(phi, w, V, out);
}